// Round 1
// baseline (5658.372 us; speedup 1.0000x reference)
//
#include <hip/hip_runtime.h>
#include <math.h>

// ---------------------------------------------------------------------------
// Decoder block, fp32 correctness-first baseline.
// N=8, K=1024, M=1024, H=8, DH=128, FF=4096. All inputs/outputs fp32.
// ---------------------------------------------------------------------------

#define TILE 128
#define GBK  16

// C[r, c] = (accum ? C[r,c] : 0) + sum_k A[r,k]*B[c,k] + bias[c], opt relu.
// A: [R, lda] row-major, B: [C, ldb] row-major (i.e. we multiply by B^T).
__global__ __launch_bounds__(256)
void gemm_f32(const float* __restrict__ A, int lda,
              const float* __restrict__ B, int ldb,
              const float* __restrict__ bias,
              float* __restrict__ C, int ldc,
              int Kd, int relu, int accum)
{
    __shared__ float As[GBK][TILE + 4];
    __shared__ float Bs[GBK][TILE + 4];

    const int tid  = threadIdx.x;
    const int tx   = tid & 15;        // col group
    const int ty   = tid >> 4;        // row group
    const int row0 = blockIdx.y * TILE;
    const int col0 = blockIdx.x * TILE;

    const int lrow  = tid >> 2;       // 0..63
    const int lpart = tid & 3;        // k chunk (4 floats)

    const float* A0 = A + (size_t)(row0 + lrow)      * lda + lpart * 4;
    const float* A1 = A + (size_t)(row0 + 64 + lrow) * lda + lpart * 4;
    const float* B0 = B + (size_t)(col0 + lrow)      * ldb + lpart * 4;
    const float* B1 = B + (size_t)(col0 + 64 + lrow) * ldb + lpart * 4;

    float acc[8][8];
#pragma unroll
    for (int i = 0; i < 8; ++i)
#pragma unroll
        for (int j = 0; j < 8; ++j) acc[i][j] = 0.f;

    for (int k0 = 0; k0 < Kd; k0 += GBK) {
        float4 a0 = *(const float4*)(A0 + k0);
        float4 a1 = *(const float4*)(A1 + k0);
        float4 b0 = *(const float4*)(B0 + k0);
        float4 b1 = *(const float4*)(B1 + k0);
        __syncthreads();   // protect LDS from previous iteration's readers
        As[lpart*4+0][lrow]     = a0.x; As[lpart*4+1][lrow]     = a0.y;
        As[lpart*4+2][lrow]     = a0.z; As[lpart*4+3][lrow]     = a0.w;
        As[lpart*4+0][lrow+64]  = a1.x; As[lpart*4+1][lrow+64]  = a1.y;
        As[lpart*4+2][lrow+64]  = a1.z; As[lpart*4+3][lrow+64]  = a1.w;
        Bs[lpart*4+0][lrow]     = b0.x; Bs[lpart*4+1][lrow]     = b0.y;
        Bs[lpart*4+2][lrow]     = b0.z; Bs[lpart*4+3][lrow]     = b0.w;
        Bs[lpart*4+0][lrow+64]  = b1.x; Bs[lpart*4+1][lrow+64]  = b1.y;
        Bs[lpart*4+2][lrow+64]  = b1.z; Bs[lpart*4+3][lrow+64]  = b1.w;
        __syncthreads();
#pragma unroll
        for (int kk = 0; kk < GBK; ++kk) {
            float a[8], b[8];
            *(float4*)&a[0] = *(const float4*)&As[kk][ty*8];
            *(float4*)&a[4] = *(const float4*)&As[kk][ty*8+4];
            *(float4*)&b[0] = *(const float4*)&Bs[kk][tx*8];
            *(float4*)&b[4] = *(const float4*)&Bs[kk][tx*8+4];
#pragma unroll
            for (int i = 0; i < 8; ++i)
#pragma unroll
                for (int j = 0; j < 8; ++j)
                    acc[i][j] = fmaf(a[i], b[j], acc[i][j]);
        }
    }

#pragma unroll
    for (int i = 0; i < 8; ++i) {
        float* crow = C + (size_t)(row0 + ty*8 + i) * ldc + (col0 + tx*8);
        const float* brow = bias ? (bias + col0 + tx*8) : (const float*)nullptr;
#pragma unroll
        for (int j = 0; j < 8; j += 4) {
            float4 v = make_float4(acc[i][j], acc[i][j+1], acc[i][j+2], acc[i][j+3]);
            if (brow)  { v.x += brow[j]; v.y += brow[j+1]; v.z += brow[j+2]; v.w += brow[j+3]; }
            if (accum) { float4 c0 = *(const float4*)(crow + j);
                         v.x += c0.x; v.y += c0.y; v.z += c0.z; v.w += c0.w; }
            if (relu)  { v.x = fmaxf(v.x, 0.f); v.y = fmaxf(v.y, 0.f);
                         v.z = fmaxf(v.z, 0.f); v.w = fmaxf(v.w, 0.f); }
            *(float4*)(crow + j) = v;
        }
    }
}

// ---------------------------------------------------------------------------
// Fused flash-style attention for one (n, h, q-block).
// Q/K/V buffers laid out [N*K, H*DH] row-major (col = h*DH + d).
// grid = (K/QB, N*H), block = 256.
// ---------------------------------------------------------------------------
#define QB  32
#define KT  32
#define DHD 128
#define ATTN_SCALE 0.08838834764831845f   // 1/sqrt(128)

__global__ __launch_bounds__(256)
void attn_f32(const float* __restrict__ Qbuf,
              const float* __restrict__ Kbuf,
              const float* __restrict__ Vbuf,
              float* __restrict__ Y)
{
    __shared__ float Qs[QB][DHD + 4];
    __shared__ float Ks[KT][DHD + 4];
    __shared__ float Vs[KT][DHD + 4];
    __shared__ float Ss[QB][KT + 4];

    const int tid = threadIdx.x;
    const int qb  = blockIdx.x;
    const int nh  = blockIdx.y;
    const int n   = nh >> 3;
    const int h   = nh & 7;

    const size_t ld = 1024;
    const float* Qg = Qbuf + (size_t)(n*1024 + qb*QB) * ld + h*DHD;
    const float* Kg = Kbuf + (size_t)(n*1024) * ld + h*DHD;
    const float* Vg = Vbuf + (size_t)(n*1024) * ld + h*DHD;
    float*       Yg = Y    + (size_t)(n*1024 + qb*QB) * ld + h*DHD;

    // stage Q tile: 32x128 floats, 4 float4 per thread
#pragma unroll
    for (int i = 0; i < 4; ++i) {
        int f  = tid + i*256;
        int r  = f >> 5;
        int c4 = f & 31;
        *(float4*)&Qs[r][c4*4] = *(const float4*)&Qg[(size_t)r*ld + c4*4];
    }

    const int row = tid >> 3;   // query row 0..31 (8 consecutive lanes/row → one wave)
    const int c8  = tid & 7;    // sub-slot 0..7

    float m = -INFINITY, l = 0.f;
    float o[16];
#pragma unroll
    for (int i = 0; i < 16; ++i) o[i] = 0.f;

    for (int kt = 0; kt < 1024; kt += KT) {
        __syncthreads();        // previous iteration readers done
#pragma unroll
        for (int i = 0; i < 4; ++i) {
            int f  = tid + i*256;
            int r  = f >> 5;
            int c4 = f & 31;
            *(float4*)&Ks[r][c4*4] = *(const float4*)&Kg[(size_t)(kt + r)*ld + c4*4];
            *(float4*)&Vs[r][c4*4] = *(const float4*)&Vg[(size_t)(kt + r)*ld + c4*4];
        }
        __syncthreads();

        // scores: this thread owns S[row][c8*4 .. c8*4+3]
        float s0 = 0.f, s1 = 0.f, s2 = 0.f, s3 = 0.f;
#pragma unroll
        for (int d4 = 0; d4 < DHD/4; ++d4) {
            float4 q  = *(const float4*)&Qs[row][d4*4];
            float4 k0 = *(const float4*)&Ks[c8*4+0][d4*4];
            float4 k1 = *(const float4*)&Ks[c8*4+1][d4*4];
            float4 k2 = *(const float4*)&Ks[c8*4+2][d4*4];
            float4 k3 = *(const float4*)&Ks[c8*4+3][d4*4];
            s0 += q.x*k0.x + q.y*k0.y + q.z*k0.z + q.w*k0.w;
            s1 += q.x*k1.x + q.y*k1.y + q.z*k1.z + q.w*k1.w;
            s2 += q.x*k2.x + q.y*k2.y + q.z*k2.z + q.w*k2.w;
            s3 += q.x*k3.x + q.y*k3.y + q.z*k3.z + q.w*k3.w;
        }
        s0 *= ATTN_SCALE; s1 *= ATTN_SCALE; s2 *= ATTN_SCALE; s3 *= ATTN_SCALE;
        *(float4*)&Ss[row][c8*4] = make_float4(s0, s1, s2, s3);
        // row group lives in ONE wave: LDS ops in-order per wave, no barrier needed

        float tmax = -INFINITY;
#pragma unroll
        for (int k4 = 0; k4 < KT/4; ++k4) {
            float4 sv = *(const float4*)&Ss[row][k4*4];
            tmax = fmaxf(tmax, fmaxf(fmaxf(sv.x, sv.y), fmaxf(sv.z, sv.w)));
        }
        float mn   = fmaxf(m, tmax);
        float corr = __expf(m - mn);      // 0 on first tile (m = -inf)
        float p0 = __expf(s0 - mn), p1 = __expf(s1 - mn);
        float p2 = __expf(s2 - mn), p3 = __expf(s3 - mn);
        *(float4*)&Ss[row][c8*4] = make_float4(p0, p1, p2, p3);
        float psum = p0 + p1 + p2 + p3;
        psum += __shfl_xor(psum, 1);
        psum += __shfl_xor(psum, 2);
        psum += __shfl_xor(psum, 4);
        l = l * corr + psum;
        m = mn;
#pragma unroll
        for (int i = 0; i < 16; ++i) o[i] *= corr;

        // PV: o[j] += P[row][k] * V[k][c8*16 + j]
#pragma unroll 8
        for (int k = 0; k < KT; ++k) {
            float p  = Ss[row][k];
            float4 v0 = *(const float4*)&Vs[k][c8*16 + 0];
            float4 v1 = *(const float4*)&Vs[k][c8*16 + 4];
            float4 v2 = *(const float4*)&Vs[k][c8*16 + 8];
            float4 v3 = *(const float4*)&Vs[k][c8*16 + 12];
            o[0]  = fmaf(p, v0.x, o[0]);  o[1]  = fmaf(p, v0.y, o[1]);
            o[2]  = fmaf(p, v0.z, o[2]);  o[3]  = fmaf(p, v0.w, o[3]);
            o[4]  = fmaf(p, v1.x, o[4]);  o[5]  = fmaf(p, v1.y, o[5]);
            o[6]  = fmaf(p, v1.z, o[6]);  o[7]  = fmaf(p, v1.w, o[7]);
            o[8]  = fmaf(p, v2.x, o[8]);  o[9]  = fmaf(p, v2.y, o[9]);
            o[10] = fmaf(p, v2.z, o[10]); o[11] = fmaf(p, v2.w, o[11]);
            o[12] = fmaf(p, v3.x, o[12]); o[13] = fmaf(p, v3.y, o[13]);
            o[14] = fmaf(p, v3.z, o[14]); o[15] = fmaf(p, v3.w, o[15]);
        }
    }

    float invl = 1.f / l;
#pragma unroll
    for (int j = 0; j < 16; j += 4) {
        float4 v = make_float4(o[j]*invl, o[j+1]*invl, o[j+2]*invl, o[j+3]*invl);
        *(float4*)&Yg[(size_t)row*ld + c8*16 + j] = v;
    }
}

// ---------------------------------------------------------------------------
// out[row] = LN(A[row] + B[row]) * g + beta. In-place safe (out may alias A/B:
// all reads of the row happen before the barrier; writes after).
// grid = 8192 rows, block = 256 (4 floats/thread).
// ---------------------------------------------------------------------------
__global__ __launch_bounds__(256)
void add_ln_f32(const float* A, const float* B,
                const float* g, const float* bet, float* out)
{
    const int row = blockIdx.x;
    const int tid = threadIdx.x;
    const size_t base = (size_t)row * 1024 + tid * 4;
    float4 a = *(const float4*)(A + base);
    float4 b = *(const float4*)(B + base);
    float4 x = make_float4(a.x+b.x, a.y+b.y, a.z+b.z, a.w+b.w);
    float s  = x.x + x.y + x.z + x.w;
    float ss = x.x*x.x + x.y*x.y + x.z*x.z + x.w*x.w;
#pragma unroll
    for (int off = 32; off > 0; off >>= 1) {
        s  += __shfl_down(s, off);
        ss += __shfl_down(ss, off);
    }
    __shared__ float red[8];
    const int wid = tid >> 6;
    if ((tid & 63) == 0) { red[wid] = s; red[4 + wid] = ss; }
    __syncthreads();
    float S  = red[0] + red[1] + red[2] + red[3];
    float SS = red[4] + red[5] + red[6] + red[7];
    float mean = S * (1.f/1024.f);
    float var  = SS * (1.f/1024.f) - mean*mean;
    float rstd = rsqrtf(var + 1e-10f);
    float4 gv = *(const float4*)(g + tid*4);
    float4 bv = *(const float4*)(bet + tid*4);
    float4 ov;
    ov.x = gv.x * (x.x - mean) * rstd + bv.x;
    ov.y = gv.y * (x.y - mean) * rstd + bv.y;
    ov.z = gv.z * (x.z - mean) * rstd + bv.z;
    ov.w = gv.w * (x.w - mean) * rstd + bv.w;
    *(float4*)(out + base) = ov;
}

// ---------------------------------------------------------------------------
extern "C" void kernel_launch(void* const* d_in, const int* in_sizes, int n_in,
                              void* d_out, int out_size, void* d_ws, size_t ws_size,
                              hipStream_t stream)
{
    const float* dec   = (const float*)d_in[0];
    const float* enc   = (const float*)d_in[1];
    const float* Wq_sa = (const float*)d_in[2];
    const float* bq_sa = (const float*)d_in[3];
    const float* Wk_sa = (const float*)d_in[4];
    const float* bk_sa = (const float*)d_in[5];
    const float* Wv_sa = (const float*)d_in[6];
    const float* bv_sa = (const float*)d_in[7];
    const float* Wo_sa = (const float*)d_in[8];
    const float* bo_sa = (const float*)d_in[9];
    const float* Wq_ca = (const float*)d_in[10];
    const float* bq_ca = (const float*)d_in[11];
    const float* Wk_ca = (const float*)d_in[12];
    const float* bk_ca = (const float*)d_in[13];
    const float* Wv_ca = (const float*)d_in[14];
    const float* bv_ca = (const float*)d_in[15];
    const float* Wo_ca = (const float*)d_in[16];
    const float* bo_ca = (const float*)d_in[17];
    const float* W1    = (const float*)d_in[18];
    const float* bf1   = (const float*)d_in[19];
    const float* W2    = (const float*)d_in[20];
    const float* bf2   = (const float*)d_in[21];
    const float* g1    = (const float*)d_in[22];
    const float* b1    = (const float*)d_in[23];
    const float* g2    = (const float*)d_in[24];
    const float* b2    = (const float*)d_in[25];
    const float* g3    = (const float*)d_in[26];
    const float* b3    = (const float*)d_in[27];

    float* out = (float*)d_out;
    float* ws  = (float*)d_ws;
    const size_t S = (size_t)8192 * 1024;
    float* X1 = ws;           // x1 / x2 (in-place LN reuse)
    float* Qb = ws + S;       // q / attn-proj / FF hidden chunk
    float* Kb = ws + 2*S;     // k
    float* Vb = ws + 3*S;     // v      → ws requirement: 4*S floats = 134 MB

    dim3 blk(256, 1, 1);
    dim3 gg(1024/TILE, 8192/TILE, 1);    // GEMMs with 1024 output cols
    dim3 ga(32, 64, 1);                  // attention grid

    // ---- self-attention ----
    gemm_f32<<<gg, blk, 0, stream>>>(dec, 1024, Wq_sa, 1024, bq_sa, Qb, 1024, 1024, 0, 0);
    gemm_f32<<<gg, blk, 0, stream>>>(dec, 1024, Wk_sa, 1024, bk_sa, Kb, 1024, 1024, 0, 0);
    gemm_f32<<<gg, blk, 0, stream>>>(dec, 1024, Wv_sa, 1024, bv_sa, Vb, 1024, 1024, 0, 0);
    attn_f32<<<ga, blk, 0, stream>>>(Qb, Kb, Vb, out);                 // Y → d_out scratch
    gemm_f32<<<gg, blk, 0, stream>>>(out, 1024, Wo_sa, 1024, bo_sa, Qb, 1024, 1024, 0, 0);
    add_ln_f32<<<8192, blk, 0, stream>>>(dec, Qb, g1, b1, X1);         // x1

    // ---- cross-attention ----
    gemm_f32<<<gg, blk, 0, stream>>>(X1,  1024, Wq_ca, 1024, bq_ca, Qb, 1024, 1024, 0, 0);
    gemm_f32<<<gg, blk, 0, stream>>>(enc, 1024, Wk_ca, 1024, bk_ca, Kb, 1024, 1024, 0, 0);
    gemm_f32<<<gg, blk, 0, stream>>>(enc, 1024, Wv_ca, 1024, bv_ca, Vb, 1024, 1024, 0, 0);
    attn_f32<<<ga, blk, 0, stream>>>(Qb, Kb, Vb, out);
    gemm_f32<<<gg, blk, 0, stream>>>(out, 1024, Wo_ca, 1024, bo_ca, Qb, 1024, 1024, 0, 0);
    add_ln_f32<<<8192, blk, 0, stream>>>(X1, Qb, g2, b2, X1);          // x2 (in-place)

    // ---- feed-forward, chunked over FF dim (4 x 1024) to cap workspace ----
    for (int c = 0; c < 4; ++c) {
        gemm_f32<<<gg, blk, 0, stream>>>(X1, 1024,
                                         W1 + (size_t)c*1024*1024, 1024,
                                         bf1 + c*1024,
                                         Qb, 1024, 1024, /*relu=*/1, /*accum=*/0);
        gemm_f32<<<gg, blk, 0, stream>>>(Qb, 1024,
                                         W2 + c*1024, 4096,
                                         (c == 0) ? bf2 : (const float*)nullptr,
                                         out, 1024, 1024, /*relu=*/0, /*accum=*/(c > 0));
    }
    add_ln_f32<<<8192, blk, 0, stream>>>(X1, out, g3, b3, out);        // final LN → d_out
}